// Round 9
// baseline (273.007 us; speedup 1.0000x reference)
//
#include <hip/hip_runtime.h>
#include <math.h>

#define PB    128
#define PHW   256
#define IMG_H 1024
#define IMG_W 1024
#define NBOX  16
#define NB    8
#define EPSF  1e-12f

// ---------------- kernel 1: sgrad groups (y=0..NG-1) + downsample (y=NG) ----------------
template<int NG>
__global__ void k_pre(const float* __restrict__ gradients, const int* __restrict__ box_yx,
                      const int* __restrict__ dec, const float* __restrict__ patch,
                      float* __restrict__ s_part, float* __restrict__ small) {
    int g = blockIdx.y;
    int t = blockIdx.x * blockDim.x + threadIdx.x;      // 0 .. 49151
    if (t >= PB * PB * 3) return;
    int c    = t % 3;
    int rest = t / 3;
    int j    = rest % PB;
    int i    = rest / PB;

    if (g == NG) {
        // ---- antialiased bilinear downsample 256 -> 128 of patch ----
        float sy = 2.f * i + 0.5f;
        float sx = 2.f * j + 0.5f;
        float wy[4], wx[4];
        int   iy[4], ix[4];
        int ny = 0, nx = 0;
        float wys = 0.f, wxs = 0.f;
        #pragma unroll
        for (int d = -1; d <= 2; ++d) {
            int y = 2 * i + d;
            if (y >= 0 && y < PHW) {
                float w = 1.f - 0.5f * fabsf(sy - (float)y);
                iy[ny] = y; wy[ny] = w; wys += w; ++ny;
            }
            int x = 2 * j + d;
            if (x >= 0 && x < PHW) {
                float w = 1.f - 0.5f * fabsf(sx - (float)x);
                ix[nx] = x; wx[nx] = w; wxs += w; ++nx;
            }
        }
        float acc = 0.f;
        for (int a = 0; a < ny; ++a) {
            float rowa = 0.f;
            for (int b2 = 0; b2 < nx; ++b2)
                rowa += wx[b2] * patch[(iy[a] * PHW + ix[b2]) * 3 + c];
            acc += wy[a] * rowa;
        }
        small[t] = acc / (wys * wxs);
        return;
    }

    // ---- sum of inverse-transformed gathered grad tiles (8 boxes per group) ----
    constexpr int BOXES_PER = (NB * NBOX) / NG;
    float acc = 0.f;
    #pragma unroll
    for (int m = 0; m < BOXES_PER; ++m) {
        int box = g * BOXES_PER + m;                    // flat index b*16+n
        int b   = box >> 4;
        int by = box_yx[box * 2 + 0];
        int bx = box_yx[box * 2 + 1];
        int d0 = dec[box * 3 + 0];
        int d1 = dec[box * 3 + 1];
        int d2 = dec[box * 3 + 2];
        int ii = i, jj = j;
        if (d0 > 0) { int ti = PB - 1 - jj; int tj = ii; ii = ti; jj = tj; } // rot90 k=3 eval
        if (d1 > 0) jj = PB - 1 - jj;
        if (d2 > 0) ii = PB - 1 - ii;
        const float* gb = gradients + (size_t)b * (IMG_H * IMG_W * 3);
        acc += gb[((by + ii) * IMG_W + (bx + jj)) * 3 + c];
    }
    s_part[(size_t)g * (PB * PB * 3) + t] = acc;
}

// ---------------- kernel 2: pure stream copy images -> out, 64B per thread ----------------
__global__ void k_copy4(const float4* __restrict__ in4, float4* __restrict__ out4) {
    int q = (blockIdx.x * blockDim.x + threadIdx.x) * 4;
    out4[q + 0] = in4[q + 0];
    out4[q + 1] = in4[q + 1];
    out4[q + 2] = in4[q + 2];
    out4[q + 3] = in4[q + 3];
}

// ---------------- kernel 3: paste box pixels (highest covering box wins) ----------------
__global__ void k_paste(const float* __restrict__ small, const int* __restrict__ box_yx,
                        const int* __restrict__ dec, float* __restrict__ out) {
    int box = blockIdx.y;              // flat b*NBOX+n
    int i   = blockIdx.x;              // row within box
    int j   = threadIdx.x;             // col within box
    int b   = box >> 4;
    int n   = box & (NBOX - 1);

    int by = box_yx[box * 2 + 0];
    int bx = box_yx[box * 2 + 1];
    int y  = by + i;
    int x  = bx + j;

    // skip if a LATER box of the same image covers this pixel (it owns the write)
    int base = (b << 4);
    for (int m = n + 1; m < NBOX; ++m) {
        int py = y - box_yx[(base + m) * 2 + 0];
        int px = x - box_yx[(base + m) * 2 + 1];
        if ((unsigned)py < (unsigned)PB && (unsigned)px < (unsigned)PB) return;
    }

    int d0 = dec[box * 3 + 0];
    int d1 = dec[box * 3 + 1];
    int d2 = dec[box * 3 + 2];
    int ii = i, jj = j;
    if (d2 > 0) ii = PB - 1 - ii;                    // undo flip_up_down
    if (d1 > 0) jj = PB - 1 - jj;                    // undo flip_left_right
    int si, sj;
    if (d0 > 0) { si = jj; sj = PB - 1 - ii; }       // undo rot90 k=1
    else        { si = ii; sj = jj; }

    const float* s = small + (si * PB + sj) * 3;
    float* o = out + ((size_t)b * (IMG_H * IMG_W) + (size_t)y * IMG_W + x) * 3;
    o[0] = s[0];
    o[1] = s[1];
    o[2] = s[2];
}

// ---------------- kernel 4: upsample 128->256 (summing NG partials) + TV gradient ----------------
template<int NG>
__global__ void k_final(const float* __restrict__ s_part, const float* __restrict__ patch,
                        float* __restrict__ agg) {
    int t = blockIdx.x * blockDim.x + threadIdx.x;
    if (t >= PHW * PHW * 3) return;
    int c    = t % 3;
    int rest = t / 3;
    int v    = rest % PHW;
    int u    = rest / PHW;

    float fy = 0.5f * u - 0.25f;
    float fx = 0.5f * v - 0.25f;
    int i0 = (int)floorf(fy);
    int j0 = (int)floorf(fx);
    float wy[2], wx[2];
    int   iy[2], jx[2];
    int ny = 0, nx = 0;
    float wys = 0.f, wxs = 0.f;
    #pragma unroll
    for (int d = 0; d < 2; ++d) {
        int i = i0 + d;
        if (i >= 0 && i < PB) {
            float w = 1.f - fabsf(fy - (float)i);
            iy[ny] = i; wy[ny] = w; wys += w; ++ny;
        }
        int jj = j0 + d;
        if (jj >= 0 && jj < PB) {
            float w = 1.f - fabsf(fx - (float)jj);
            jx[nx] = jj; wx[nx] = w; wxs += w; ++nx;
        }
    }
    float acc = 0.f;
    for (int a = 0; a < ny; ++a)
        for (int b2 = 0; b2 < nx; ++b2) {
            int idx = (iy[a] * PB + jx[b2]) * 3 + c;
            float sv = 0.f;
            #pragma unroll
            for (int g = 0; g < NG; ++g)
                sv += s_part[(size_t)g * (PB * PB * 3) + idx];
            acc += wy[a] * wx[b2] * sv;
        }
    acc /= (wys * wxs);

    // ---- TV-loss gradient (closed form) ----
    #define PAT(a, b) patch[((a) * PHW + (b)) * 3 + c]
    float p  = PAT(u, v);
    float dx = (v < PHW - 1) ? (p - PAT(u, v + 1)) : 0.f;
    float dy = (u < PHW - 1) ? (p - PAT(u + 1, v)) : 0.f;
    float r  = sqrtf(dx * dx + dy * dy + EPSF);
    float gsum = (dx + dy) / r;
    if (v > 0) {
        float pl  = PAT(u, v - 1);
        float dxl = pl - p;
        float dyl = (u < PHW - 1) ? (pl - PAT(u + 1, v - 1)) : 0.f;
        gsum -= dxl / sqrtf(dxl * dxl + dyl * dyl + EPSF);
    }
    if (u > 0) {
        float pu_ = PAT(u - 1, v);
        float dyu = pu_ - p;
        float dxu = (v < PHW - 1) ? (pu_ - PAT(u - 1, v + 1)) : 0.f;
        gsum -= dyu / sqrtf(dxu * dxu + dyu * dyu + EPSF);
    }
    #undef PAT
    agg[t] = acc + 0.5f * gsum;
}

extern "C" void kernel_launch(void* const* d_in, const int* in_sizes, int n_in,
                              void* d_out, int out_size, void* d_ws, size_t ws_size,
                              hipStream_t stream) {
    const float* images    = (const float*)d_in[0];
    const float* gradients = (const float*)d_in[1];
    const float* patch     = (const float*)d_in[2];
    const int*   box_yx    = (const int*)d_in[3];
    const int*   dec       = (const int*)d_in[4];

    float* out     = (float*)d_out;
    float* agg_out = out + (size_t)NB * IMG_H * IMG_W * 3;

    const size_t TILE = PB * PB * 3;   // 49152 floats
    bool big = ws_size >= TILE * (size_t)(1 + 16) * sizeof(float);

    float* small  = (float*)d_ws;
    float* s_part = small + TILE;

    if (big) {
        hipLaunchKernelGGL((k_pre<16>), dim3(192, 17), dim3(256), 0, stream,
                           gradients, box_yx, dec, patch, s_part, small);
    } else {
        hipLaunchKernelGGL((k_pre<1>), dim3(192, 2), dim3(256), 0, stream,
                           gradients, box_yx, dec, patch, s_part, small);
    }
    hipLaunchKernelGGL(k_copy4, dim3((IMG_H * IMG_W * 3 * NB) / 16 / 256), dim3(256), 0, stream,
                       (const float4*)images, (float4*)out);
    hipLaunchKernelGGL(k_paste, dim3(PB, NB * NBOX), dim3(PB), 0, stream,
                       small, box_yx, dec, out);
    if (big) {
        hipLaunchKernelGGL((k_final<16>), dim3((PHW * PHW * 3) / 256), dim3(256), 0, stream,
                           s_part, patch, agg_out);
    } else {
        hipLaunchKernelGGL((k_final<1>), dim3((PHW * PHW * 3) / 256), dim3(256), 0, stream,
                           s_part, patch, agg_out);
    }
}

// Round 10
// 268.032 us; speedup vs baseline: 1.0186x; 1.0186x over previous
//
#include <hip/hip_runtime.h>
#include <math.h>

#define PB    128
#define PHW   256
#define IMG_H 1024
#define IMG_W 1024
#define NBOX  16
#define NB    8
#define EPSF  1e-12f

// ---------------- kernel 1: sgrad groups (y=0..NG-1) + downsample (y=NG) ----------------
template<int NG>
__global__ void k_pre(const float* __restrict__ gradients, const int* __restrict__ box_yx,
                      const int* __restrict__ dec, const float* __restrict__ patch,
                      float* __restrict__ s_part, float* __restrict__ small) {
    int g = blockIdx.y;
    int t = blockIdx.x * blockDim.x + threadIdx.x;      // 0 .. 49151
    if (t >= PB * PB * 3) return;
    int c    = t % 3;
    int rest = t / 3;
    int j    = rest % PB;
    int i    = rest / PB;

    if (g == NG) {
        // ---- antialiased bilinear downsample 256 -> 128 of patch ----
        float sy = 2.f * i + 0.5f;
        float sx = 2.f * j + 0.5f;
        float wy[4], wx[4];
        int   iy[4], ix[4];
        int ny = 0, nx = 0;
        float wys = 0.f, wxs = 0.f;
        #pragma unroll
        for (int d = -1; d <= 2; ++d) {
            int y = 2 * i + d;
            if (y >= 0 && y < PHW) {
                float w = 1.f - 0.5f * fabsf(sy - (float)y);
                iy[ny] = y; wy[ny] = w; wys += w; ++ny;
            }
            int x = 2 * j + d;
            if (x >= 0 && x < PHW) {
                float w = 1.f - 0.5f * fabsf(sx - (float)x);
                ix[nx] = x; wx[nx] = w; wxs += w; ++nx;
            }
        }
        float acc = 0.f;
        for (int a = 0; a < ny; ++a) {
            float rowa = 0.f;
            for (int b2 = 0; b2 < nx; ++b2)
                rowa += wx[b2] * patch[(iy[a] * PHW + ix[b2]) * 3 + c];
            acc += wy[a] * rowa;
        }
        small[t] = acc / (wys * wxs);
        return;
    }

    // ---- sum of inverse-transformed gathered grad tiles (8 boxes per group) ----
    constexpr int BOXES_PER = (NB * NBOX) / NG;
    float acc = 0.f;
    #pragma unroll
    for (int m = 0; m < BOXES_PER; ++m) {
        int box = g * BOXES_PER + m;                    // flat index b*16+n
        int b   = box >> 4;
        int by = box_yx[box * 2 + 0];
        int bx = box_yx[box * 2 + 1];
        int d0 = dec[box * 3 + 0];
        int d1 = dec[box * 3 + 1];
        int d2 = dec[box * 3 + 2];
        int ii = i, jj = j;
        if (d0 > 0) { int ti = PB - 1 - jj; int tj = ii; ii = ti; jj = tj; } // rot90 k=3 eval
        if (d1 > 0) jj = PB - 1 - jj;
        if (d2 > 0) ii = PB - 1 - ii;
        const float* gb = gradients + (size_t)b * (IMG_H * IMG_W * 3);
        acc += gb[((by + ii) * IMG_W + (bx + jj)) * 3 + c];
    }
    s_part[(size_t)g * (PB * PB * 3) + t] = acc;
}

// ------- kernel 2: stream copy images -> out, 4 float4/thread, COALESCED per instr -------
__global__ void k_copyc(const float4* __restrict__ in4, float4* __restrict__ out4) {
    int base = blockIdx.x * (blockDim.x * 4) + threadIdx.x;
    out4[base + 0 * 256] = in4[base + 0 * 256];
    out4[base + 1 * 256] = in4[base + 1 * 256];
    out4[base + 2 * 256] = in4[base + 2 * 256];
    out4[base + 3 * 256] = in4[base + 3 * 256];
}

// ---------------- kernel 3: paste box pixels (highest covering box wins) ----------------
__global__ void k_paste(const float* __restrict__ small, const int* __restrict__ box_yx,
                        const int* __restrict__ dec, float* __restrict__ out) {
    int box = blockIdx.y;              // flat b*NBOX+n
    int i   = blockIdx.x;              // row within box
    int j   = threadIdx.x;             // col within box
    int b   = box >> 4;
    int n   = box & (NBOX - 1);

    int by = box_yx[box * 2 + 0];
    int bx = box_yx[box * 2 + 1];
    int y  = by + i;
    int x  = bx + j;

    // skip if a LATER box of the same image covers this pixel (it owns the write)
    int base = (b << 4);
    for (int m = n + 1; m < NBOX; ++m) {
        int py = y - box_yx[(base + m) * 2 + 0];
        int px = x - box_yx[(base + m) * 2 + 1];
        if ((unsigned)py < (unsigned)PB && (unsigned)px < (unsigned)PB) return;
    }

    int d0 = dec[box * 3 + 0];
    int d1 = dec[box * 3 + 1];
    int d2 = dec[box * 3 + 2];
    int ii = i, jj = j;
    if (d2 > 0) ii = PB - 1 - ii;                    // undo flip_up_down
    if (d1 > 0) jj = PB - 1 - jj;                    // undo flip_left_right
    int si, sj;
    if (d0 > 0) { si = jj; sj = PB - 1 - ii; }       // undo rot90 k=1
    else        { si = ii; sj = jj; }

    const float* s = small + (si * PB + sj) * 3;
    float* o = out + ((size_t)b * (IMG_H * IMG_W) + (size_t)y * IMG_W + x) * 3;
    o[0] = s[0];
    o[1] = s[1];
    o[2] = s[2];
}

// ---------------- kernel 4: upsample 128->256 (summing NG partials) + TV gradient ----------------
template<int NG>
__global__ void k_final(const float* __restrict__ s_part, const float* __restrict__ patch,
                        float* __restrict__ agg) {
    int t = blockIdx.x * blockDim.x + threadIdx.x;
    if (t >= PHW * PHW * 3) return;
    int c    = t % 3;
    int rest = t / 3;
    int v    = rest % PHW;
    int u    = rest / PHW;

    float fy = 0.5f * u - 0.25f;
    float fx = 0.5f * v - 0.25f;
    int i0 = (int)floorf(fy);
    int j0 = (int)floorf(fx);
    float wy[2], wx[2];
    int   iy[2], jx[2];
    int ny = 0, nx = 0;
    float wys = 0.f, wxs = 0.f;
    #pragma unroll
    for (int d = 0; d < 2; ++d) {
        int i = i0 + d;
        if (i >= 0 && i < PB) {
            float w = 1.f - fabsf(fy - (float)i);
            iy[ny] = i; wy[ny] = w; wys += w; ++ny;
        }
        int jj = j0 + d;
        if (jj >= 0 && jj < PB) {
            float w = 1.f - fabsf(fx - (float)jj);
            jx[nx] = jj; wx[nx] = w; wxs += w; ++nx;
        }
    }
    float acc = 0.f;
    for (int a = 0; a < ny; ++a)
        for (int b2 = 0; b2 < nx; ++b2) {
            int idx = (iy[a] * PB + jx[b2]) * 3 + c;
            float sv = 0.f;
            #pragma unroll
            for (int g = 0; g < NG; ++g)
                sv += s_part[(size_t)g * (PB * PB * 3) + idx];
            acc += wy[a] * wx[b2] * sv;
        }
    acc /= (wys * wxs);

    // ---- TV-loss gradient (closed form) ----
    #define PAT(a, b) patch[((a) * PHW + (b)) * 3 + c]
    float p  = PAT(u, v);
    float dx = (v < PHW - 1) ? (p - PAT(u, v + 1)) : 0.f;
    float dy = (u < PHW - 1) ? (p - PAT(u + 1, v)) : 0.f;
    float r  = sqrtf(dx * dx + dy * dy + EPSF);
    float gsum = (dx + dy) / r;
    if (v > 0) {
        float pl  = PAT(u, v - 1);
        float dxl = pl - p;
        float dyl = (u < PHW - 1) ? (pl - PAT(u + 1, v - 1)) : 0.f;
        gsum -= dxl / sqrtf(dxl * dxl + dyl * dyl + EPSF);
    }
    if (u > 0) {
        float pu_ = PAT(u - 1, v);
        float dyu = pu_ - p;
        float dxu = (v < PHW - 1) ? (pu_ - PAT(u - 1, v + 1)) : 0.f;
        gsum -= dyu / sqrtf(dxu * dxu + dyu * dyu + EPSF);
    }
    #undef PAT
    agg[t] = acc + 0.5f * gsum;
}

extern "C" void kernel_launch(void* const* d_in, const int* in_sizes, int n_in,
                              void* d_out, int out_size, void* d_ws, size_t ws_size,
                              hipStream_t stream) {
    const float* images    = (const float*)d_in[0];
    const float* gradients = (const float*)d_in[1];
    const float* patch     = (const float*)d_in[2];
    const int*   box_yx    = (const int*)d_in[3];
    const int*   dec       = (const int*)d_in[4];

    float* out     = (float*)d_out;
    float* agg_out = out + (size_t)NB * IMG_H * IMG_W * 3;

    const size_t TILE = PB * PB * 3;   // 49152 floats
    bool big = ws_size >= TILE * (size_t)(1 + 16) * sizeof(float);

    float* small  = (float*)d_ws;
    float* s_part = small + TILE;

    if (big) {
        hipLaunchKernelGGL((k_pre<16>), dim3(192, 17), dim3(256), 0, stream,
                           gradients, box_yx, dec, patch, s_part, small);
    } else {
        hipLaunchKernelGGL((k_pre<1>), dim3(192, 2), dim3(256), 0, stream,
                           gradients, box_yx, dec, patch, s_part, small);
    }
    hipLaunchKernelGGL(k_copyc, dim3((IMG_H * IMG_W * 3 * NB) / 16 / 256), dim3(256), 0, stream,
                       (const float4*)images, (float4*)out);
    hipLaunchKernelGGL(k_paste, dim3(PB, NB * NBOX), dim3(PB), 0, stream,
                       small, box_yx, dec, out);
    if (big) {
        hipLaunchKernelGGL((k_final<16>), dim3((PHW * PHW * 3) / 256), dim3(256), 0, stream,
                           s_part, patch, agg_out);
    } else {
        hipLaunchKernelGGL((k_final<1>), dim3((PHW * PHW * 3) / 256), dim3(256), 0, stream,
                           s_part, patch, agg_out);
    }
}